// Round 4
// baseline (617.320 us; speedup 1.0000x reference)
//
#include <hip/hip_runtime.h>
#include <hip/hip_bf16.h>

// sLSTM block, MI355X. One fused bf16 MFMA GEMM
//   P[g] = [x|h] (4096x4096) @ [Wg|Rg]^T (2048x4096), g in {z,i,f,o}
// with gating epilogue fused (LDS exchange of the 4 gate tiles).
// R7: two independent barrier domains per CU (256-thr blocks, 2 blocks/CU).
//   Evidence: R6 per-K-tile time = MFMA cycles + LDS cycles summed -> the
//   single 8-wave barrier-locked block serializes the two pipes. Two
//   co-resident blocks drift out of phase and overlap MFMA vs LDS/stage,
//   and overlap one block's epilogue with the other's K-loop.
//   - block: 4 waves = 4 gates; tile 128 rows x 64 cols x 4 gates; BK=32
//   - per-wave output 128x64 (acc[8][4], 128 VGPR), grid (32,32)=1024 blocks
//   - LDS 72KB: 3 x 24KB buffers (A 8KB + B 16KB), chunk pair-packed layout,
//     conflict-free ds_read_b128, linear global_load_lds dest
//   - counted s_waitcnt vmcnt(6), 2 phases/K-tile, setprio around MFMA
// ws: A_bf16 [4096][4096] @0 (32MB) | Wb_bf16 [4][2048][4096] @32MB (64MB)
//     | Bb fp32 [4][2048] @96MB.

#define BATCH 4096
#define NHID  2048
#define KDIM  4096
#define NTOT  8388608L   // BATCH*NHID
#define AW_OFS 16777216  // elements from A base to W base in ws
#define BUFSZ 24576      // one stage buffer: A 8KB + B 16KB

typedef float  f32x4   __attribute__((ext_vector_type(4)));
typedef short  short8  __attribute__((ext_vector_type(8)));
typedef unsigned short ushort8 __attribute__((ext_vector_type(8)));

#define GL_LDS16(gp, lp)                                                      \
    __builtin_amdgcn_global_load_lds(                                         \
        (const __attribute__((address_space(1))) void*)(gp),                  \
        (__attribute__((address_space(3))) void*)(lp), 16, 0, 0)

__device__ __forceinline__ unsigned short f2bf(float f) {
    unsigned u = __float_as_uint(f);
    unsigned r = (u + 0x7fffu + ((u >> 16) & 1u)) >> 16;   // RNE
    return (unsigned short)r;
}

// ---- fp32 -> bf16 pack of A = [x | h_prev], 4096 x 4096 -------------------
__global__ void convA_kernel(const float* __restrict__ x,
                             const float* __restrict__ h,
                             unsigned short* __restrict__ A) {
    int gid = blockIdx.x * 256 + threadIdx.x;       // 4096*512 groups of 8
    int row = gid >> 9;
    int col = (gid & 511) << 3;
    const float* src = (col < 2048) ? (x + (long)row * 2048 + col)
                                    : (h + (long)row * 2048 + (col - 2048));
    f32x4 v0 = __builtin_nontemporal_load((const f32x4*)src);
    f32x4 v1 = __builtin_nontemporal_load((const f32x4*)src + 1);
    ushort8 o;
    o[0] = f2bf(v0[0]); o[1] = f2bf(v0[1]); o[2] = f2bf(v0[2]); o[3] = f2bf(v0[3]);
    o[4] = f2bf(v1[0]); o[5] = f2bf(v1[1]); o[6] = f2bf(v1[2]); o[7] = f2bf(v1[3]);
    *(ushort8*)(A + ((long)row << 12) + col) = o;
}

// ---- fp32 -> bf16 pack of Wb[g][j][k] (k<2048: Wg, k>=2048: Rg) -----------
__global__ void convW_kernel(const float* __restrict__ w0, const float* __restrict__ w1,
                             const float* __restrict__ w2, const float* __restrict__ w3,
                             const float* __restrict__ w4, const float* __restrict__ w5,
                             const float* __restrict__ w6, const float* __restrict__ w7,
                             unsigned short* __restrict__ Wb) {
    int z = blockIdx.y;                              // 0..3 = Wzx..Wox, 4..7 = Rzh..Roh
    const float* src;
    switch (z) {
        case 0: src = w0; break; case 1: src = w1; break;
        case 2: src = w2; break; case 3: src = w3; break;
        case 4: src = w4; break; case 5: src = w5; break;
        case 6: src = w6; break; default: src = w7; break;
    }
    int gid = blockIdx.x * 256 + threadIdx.x;        // 2048*256 groups of 8
    int row = gid >> 8;
    int col = (gid & 255) << 3;
    const float* p = src + (long)row * 2048 + col;
    f32x4 v0 = __builtin_nontemporal_load((const f32x4*)p);
    f32x4 v1 = __builtin_nontemporal_load((const f32x4*)p + 1);
    ushort8 o;
    o[0] = f2bf(v0[0]); o[1] = f2bf(v0[1]); o[2] = f2bf(v0[2]); o[3] = f2bf(v0[3]);
    o[4] = f2bf(v1[0]); o[5] = f2bf(v1[1]); o[6] = f2bf(v1[2]); o[7] = f2bf(v1[3]);
    int g = z & 3, hf = z >> 2;
    *(ushort8*)(Wb + (long)g * NHID * KDIM + (long)row * KDIM + hf * 2048 + col) = o;
}

// ---- combined bias Bb[g][j] = Wg_b[j] + Rg_b[j] ---------------------------
__global__ void bias_kernel(const float* __restrict__ b0, const float* __restrict__ b1,
                            const float* __restrict__ b2, const float* __restrict__ b3,
                            const float* __restrict__ r0, const float* __restrict__ r1,
                            const float* __restrict__ r2, const float* __restrict__ r3,
                            float* __restrict__ Bb) {
    int gid = blockIdx.x * 256 + threadIdx.x;        // 0..8191
    int g = gid >> 11, j = gid & 2047;
    const float *wb, *rb;
    switch (g) {
        case 0: wb = b0; rb = r0; break; case 1: wb = b1; rb = r1; break;
        case 2: wb = b2; rb = r2; break; default: wb = b3; rb = r3; break;
    }
    Bb[gid] = wb[j] + rb[j];
}

// ---- fused GEMM (4 gates) + sLSTM epilogue --------------------------------
// block: 256 threads = 4 waves; wave = gate. Wave computes 128x64 of its gate
// (8x4 of 16x16x32 MFMA). grid: (32 row-tiles of 128, 32 col-tiles of 64).
// LDS buffer layout (chunk pair-packed, conflict-free, linear-dest staging):
//   A: addr(r,c) = (r>>1)*128 + ((((r&1)<<2)|c) ^ ((r>>1)&7))*16, r<128, c<4
//   B: 8192 + same formula with gr<256 (gr = gate*64 + col_in_gate)
// Read offsets collapse to aBase + mt*1024 (A) / 8192+gate*4096+nt*1024+aBase (B)
// where aBase = (lm>>1)*128 + ((((lm&1)<<2)|quad)^((lm>>1)&7))*16.
// Staging: 24 x 1KB loads/tile; load id: lds off = id*1024 + lane*16 (linear).
// Pipeline: triple buffer; iter kt reads buf[kt%3], stages tile kt+2 (3 loads
// per phase); end-of-iter vmcnt(6) retires tile kt+1, leaves kt+2 in flight.
__global__ __launch_bounds__(256, 2) void slstm_kernel(
    const __hip_bfloat16* __restrict__ A,    // [4096][4096], W follows at +AW_OFS
    const float* __restrict__ Bb,            // [4][2048]
    const float* __restrict__ c_prev,
    const float* __restrict__ n_prev,
    const float* __restrict__ m_prev,
    float* __restrict__ out)                 // h | c | n | m
{
    __shared__ uint4 smem4[(3 * BUFSZ) / 16];  // 72 KB -> 2 blocks/CU
    char* smem = (char*)smem4;

    const int tid  = threadIdx.x;
    const int lane = tid & 63;
    const int gate = tid >> 6;     // wave id 0..3 = gate
    const int lm   = lane & 15;
    const int quad = lane >> 4;

    const int row0 = blockIdx.x * 128;  // batch rows
    const int col0 = blockIdx.y * 64;   // hidden cols

    // fragment ds_read base (same for A and B by construction)
    const int aBase = (lm >> 1) * 128 +
                      (((((lm & 1) << 2) | quad) ^ ((lm >> 1) & 7))) * 16;
    const int bBase = 8192 + gate * 4096 + aBase;

    // staging: 24 loads of 1KB per tile (ids 0..7 -> A, 8..23 -> B);
    // wave w issues ids w*6..w*6+5.
    const int s = lane & 7, hh8 = (lane >> 3) & 7, v = s ^ hh8;
    int gofs[6], lofs[6];
#pragma unroll
    for (int t = 0; t < 6; ++t) {
        int id = gate * 6 + t;
        lofs[t] = id * 1024 + lane * 16;
        if (id < 8) {
            int r = (id * 8 + (lane >> 3)) * 2 + (v >> 2);   // 0..127
            gofs[t] = (row0 + r) * KDIM + (v & 3) * 8;
        } else {
            int bid = id - 8;
            int gr = (bid * 8 + (lane >> 3)) * 2 + (v >> 2); // 0..255
            int g = gr >> 6, rr = gr & 63;
            gofs[t] = AW_OFS + g * (NHID * KDIM) + (col0 + rr) * KDIM + (v & 3) * 8;
        }
    }

    f32x4 acc[8][4];
#pragma unroll
    for (int mt = 0; mt < 8; ++mt)
#pragma unroll
        for (int nt = 0; nt < 4; ++nt)
#pragma unroll
            for (int r = 0; r < 4; ++r) acc[mt][nt][r] = 0.0f;

    // prologue: stage tile 0 -> buf0, tile 1 -> buf1
#pragma unroll
    for (int t = 0; t < 6; ++t) GL_LDS16(A + gofs[t], smem + lofs[t]);
#pragma unroll
    for (int t = 0; t < 6; ++t) GL_LDS16(A + gofs[t] + 32, smem + BUFSZ + lofs[t]);
    asm volatile("s_waitcnt vmcnt(6)" ::: "memory");   // tile 0 landed
    __builtin_amdgcn_s_barrier();

    int cur = 0, nxt = BUFSZ, wrt = 2 * BUFSZ;
    for (int kt = 0; kt < 128; ++kt) {
        const char* base = smem + cur;
        char* wb = smem + wrt;
        const int kS = (kt + 2) * 32;
        const bool stage_ok = (kt <= 125);

        // ---- phase 0: mt 0-3 ----
        short8 bf[4], af[4];
#pragma unroll
        for (int nt = 0; nt < 4; ++nt)
            bf[nt] = *(const short8*)(base + bBase + nt * 1024);
#pragma unroll
        for (int m2 = 0; m2 < 4; ++m2)
            af[m2] = *(const short8*)(base + aBase + m2 * 1024);
        if (stage_ok) {
            GL_LDS16(A + gofs[0] + kS, wb + lofs[0]);
            GL_LDS16(A + gofs[1] + kS, wb + lofs[1]);
            GL_LDS16(A + gofs[2] + kS, wb + lofs[2]);
        }
        __builtin_amdgcn_s_barrier();
        __builtin_amdgcn_s_setprio(1);
#pragma unroll
        for (int m2 = 0; m2 < 4; ++m2)
#pragma unroll
            for (int nt = 0; nt < 4; ++nt)
                acc[m2][nt] = __builtin_amdgcn_mfma_f32_16x16x32_bf16(
                    af[m2], bf[nt], acc[m2][nt], 0, 0, 0);
        __builtin_amdgcn_s_setprio(0);
        __builtin_amdgcn_s_barrier();

        // ---- phase 1: mt 4-7 ----
#pragma unroll
        for (int m2 = 0; m2 < 4; ++m2)
            af[m2] = *(const short8*)(base + aBase + (4 + m2) * 1024);
        if (stage_ok) {
            GL_LDS16(A + gofs[3] + kS, wb + lofs[3]);
            GL_LDS16(A + gofs[4] + kS, wb + lofs[4]);
            GL_LDS16(A + gofs[5] + kS, wb + lofs[5]);
        }
        // retire tile kt+1 (next iter's read buffer); leave kt+2 in flight
        if (kt <= 125)      asm volatile("s_waitcnt vmcnt(6)" ::: "memory");
        else if (kt == 126) asm volatile("s_waitcnt vmcnt(0)" ::: "memory");
        __builtin_amdgcn_s_barrier();
        __builtin_amdgcn_s_setprio(1);
#pragma unroll
        for (int m2 = 0; m2 < 4; ++m2)
#pragma unroll
            for (int nt = 0; nt < 4; ++nt)
                acc[4 + m2][nt] = __builtin_amdgcn_mfma_f32_16x16x32_bf16(
                    af[m2], bf[nt], acc[4 + m2][nt], 0, 0, 0);
        __builtin_amdgcn_s_setprio(0);
        __builtin_amdgcn_s_barrier();

        int t0 = cur; cur = nxt; nxt = wrt; wrt = t0;
    }

    // ---- epilogue: exchange gate tiles through LDS, compute h,c,n,m ----
    float* exch = (float*)smem;   // [4 gates][16 rows][65] floats (16.6KB)
#pragma unroll
    for (int mt = 0; mt < 8; ++mt) {
        __syncthreads();
#pragma unroll
        for (int nt = 0; nt < 4; ++nt)
#pragma unroll
            for (int r = 0; r < 4; ++r)
                exch[(gate * 16 + quad * 4 + r) * 65 + nt * 16 + lm] =
                    acc[mt][nt][r];
        __syncthreads();
#pragma unroll
        for (int q = 0; q < 4; ++q) {
            int e   = q * 256 + tid;          // 0..1023
            int row = e >> 6, col = e & 63;
            int R = row0 + mt * 16 + row;
            int C = col0 + col;
            long idx = (long)R * NHID + C;
            float zp = exch[(0 * 16 + row) * 65 + col] + Bb[C];
            float ip = exch[(1 * 16 + row) * 65 + col] + Bb[2048 + C];
            float fp = exch[(2 * 16 + row) * 65 + col] + Bb[4096 + C];
            float op = exch[(3 * 16 + row) * 65 + col] + Bb[6144 + C];
            float cp = __builtin_nontemporal_load(c_prev + idx);
            float np = __builtin_nontemporal_load(n_prev + idx);
            float mp = __builtin_nontemporal_load(m_prev + idx);
            float z  = tanhf(zp);
            float o  = 1.0f / (1.0f + __expf(-op));
            float mm = fmaxf(fp + mp, ip);
            float ih = __expf(ip - mm);
            float fh = __expf(fp + mp - mm);
            float cc = fh * cp + ih * z;
            float nn = fh * np + ih;
            float hhv = o * cc / nn;
            __builtin_nontemporal_store(hhv, out + idx);
            __builtin_nontemporal_store(cc, out + NTOT + idx);
            __builtin_nontemporal_store(nn, out + 2 * NTOT + idx);
            __builtin_nontemporal_store(mm, out + 3 * NTOT + idx);
        }
    }
}

extern "C" void kernel_launch(void* const* d_in, const int* in_sizes, int n_in,
                              void* d_out, int out_size, void* d_ws, size_t ws_size,
                              hipStream_t stream) {
    const float* x      = (const float*)d_in[0];
    const float* h_prev = (const float*)d_in[1];
    const float* c_prev = (const float*)d_in[2];
    const float* n_prev = (const float*)d_in[3];
    const float* m_prev = (const float*)d_in[4];
    unsigned short* A  = (unsigned short*)d_ws;                          // 32 MB
    unsigned short* Wb = (unsigned short*)((char*)d_ws + 33554432);      // 64 MB
    float*          Bb = (float*)((char*)d_ws + 100663296);              // 32 KB

    convA_kernel<<<8192, 256, 0, stream>>>(x, h_prev, A);
    convW_kernel<<<dim3(2048, 8), 256, 0, stream>>>(
        (const float*)d_in[5], (const float*)d_in[7], (const float*)d_in[9],
        (const float*)d_in[11], (const float*)d_in[13], (const float*)d_in[15],
        (const float*)d_in[17], (const float*)d_in[19], Wb);
    bias_kernel<<<32, 256, 0, stream>>>(
        (const float*)d_in[6], (const float*)d_in[8], (const float*)d_in[10],
        (const float*)d_in[12], (const float*)d_in[14], (const float*)d_in[16],
        (const float*)d_in[18], (const float*)d_in[20], Bb);

    slstm_kernel<<<dim3(32, 32), 256, 0, stream>>>(
        (const __hip_bfloat16*)A, Bb, c_prev, n_prev, m_prev, (float*)d_out);
}